// Round 1
// baseline (83.769 us; speedup 1.0000x reference)
//
#include <hip/hip_runtime.h>
#include <math.h>

// Problem shape (fixed by harness setup_inputs): B=8, N=M=4096, D=3, fp32.
#define B_SZ 8
#define N_SZ 4096
#define M_SZ 4096
#define NQ (B_SZ * N_SZ)            // 32768 queries per direction
#define TOT (2 * NQ)                // 65536 total queries

#define THREADS 256
#define QPT 8                       // queries per thread
#define QPB (THREADS * QPT)         // 2048 queries per block
#define ITILES (N_SZ / QPB)         // 2
#define JTILE 256                   // targets staged in LDS per block
#define NJT (M_SZ / JTILE)          // 16 target tiles (= partials per query)
#define JPAIRS (JTILE / 2)          // 128 packed target pairs

#define NBLK2 (TOT / 256)           // 256 phase-2 blocks

typedef float f32x2 __attribute__((ext_vector_type(2)));

// ws layout (floats): part[g * TOT + q], g in [0,NJT) -> 4 MB.
// Every slot is written by phase 1, so no ws init needed. No ws atomics.
//
// score(q,t) = t^2/2 - q.t ; after the tile loop we add q^2/2 -> d^2/2.
//
// Packing axis: two TARGETS per f32x2 lane-pair (queries broadcast-packed in
// registers). The min over the 2 packed targets folds into the row-min
// accumulator as one v_min3_f32: per query-target pair the loop costs
// 1.5 pk_fma + 0.5 min3 = 2.0 issue slots (was 2.5 with query-packing).
//
// grid: x = ITILES*NJT (32), y = B (8), z = dir (2)  -> 512 blocks.
__global__ __launch_bounds__(THREADS)
void chamfer_partial_kernel(const float* __restrict__ pred,
                            const float* __restrict__ tgt,
                            float* __restrict__ part,
                            float* __restrict__ out)
{
    const int b   = blockIdx.y;
    const int dir = blockIdx.z;

    // Zero the output accumulator for phase 2's atomics (stream-ordered:
    // this kernel fully completes before phase 2 starts).
    if (blockIdx.x == 0 && b == 0 && dir == 0 && threadIdx.x == 0)
        out[0] = 0.0f;

    const float* Q;
    const float* Db;
    int qoff;
    if (dir == 0) { Q = pred + (size_t)b * N_SZ * 3; Db = tgt  + (size_t)b * M_SZ * 3; qoff = b * N_SZ; }
    else          { Q = tgt  + (size_t)b * M_SZ * 3; Db = pred + (size_t)b * N_SZ * 3; qoff = NQ + b * M_SZ; }

    const int itile = blockIdx.x >> 4;          // / NJT
    const int g     = blockIdx.x & (NJT - 1);

    // Pair-packed target tile: spA[p] = {x0,x1,y0,y1}, spB[p] = {z0,z1,h0,h1}
    // (h = |t|^2/2). Packed at staging time so the hot loop needs zero
    // packing movs: f32x2 sub-vectors fall out of the b128 register quads.
    __shared__ float4 spA[JPAIRS];
    __shared__ float4 spB[JPAIRS];
    {
        const int k = threadIdx.x;              // target index within tile
        const float* s = Db + (size_t)(g * JTILE + k) * 3;
        float x = s[0], y = s[1], z = s[2];
        float h = 0.5f * (x * x + y * y + z * z);
        float* A  = (float*)&spA[k >> 1];
        float* Bv = (float*)&spB[k >> 1];
        const int hsel = k & 1;                 // which half of the pair
        A[hsel]      = x;
        A[2 + hsel]  = y;
        Bv[hsel]     = z;
        Bv[2 + hsel] = h;
    }

    // 8 queries per thread: negated coords broadcast-packed {v,v} so the
    // pk_fma operands need no in-loop duplication; q^2/2 folded in at store.
    f32x2 qxn[QPT], qyn[QPT], qzn[QPT];
    float q2h[QPT], mn[QPT];
    const int qbase = itile * QPB + threadIdx.x;
#pragma unroll
    for (int i = 0; i < QPT; ++i) {
        const int qi = qbase + i * THREADS;
        float x = Q[qi * 3 + 0], y = Q[qi * 3 + 1], z = Q[qi * 3 + 2];
        qxn[i] = { -x, -x };
        qyn[i] = { -y, -y };
        qzn[i] = { -z, -z };
        q2h[i] = 0.5f * (x * x + y * y + z * z);
        mn[i]  = 3.0e38f;
    }
    __syncthreads();

    // Inner loop per target-pair: 2 broadcast ds_read_b128; per query
    // 3 pk_fma + 1 min3 -> 2.0 VALU issue slots per point-pair.
#pragma unroll 4
    for (int j = 0; j < JPAIRS; ++j) {
        float4 A  = spA[j];
        float4 Bv = spB[j];
        f32x2 tx = { A.x,  A.y  };
        f32x2 ty = { A.z,  A.w  };
        f32x2 tz = { Bv.x, Bv.y };
        f32x2 th = { Bv.z, Bv.w };
#pragma unroll
        for (int i = 0; i < QPT; ++i) {
            f32x2 sc = th + qxn[i] * tx;
            sc += qyn[i] * ty;
            sc += qzn[i] * tz;
            mn[i] = fminf(mn[i], fminf(sc.x, sc.y));   // fuses to v_min3_f32
        }
    }

    // Fold q^2/2 -> partial d^2/2; plain coalesced stores (no atomics).
    float* pg = part + (size_t)g * TOT + qoff;
#pragma unroll
    for (int i = 0; i < QPT; ++i)
        pg[qbase + i * THREADS] = mn[i] + q2h[i];
}

// Phase 2 (phase 3 fused in): one query per thread; 16 coalesced loads;
// block sum; one atomicAdd per block (256 total, no contention).
__global__ __launch_bounds__(256)
void chamfer_combine_kernel(const float* __restrict__ part,
                            float* __restrict__ out)
{
    const int q = blockIdx.x * 256 + threadIdx.x;
    float m = 3.0e38f;
#pragma unroll
    for (int g = 0; g < NJT; ++g) m = fminf(m, part[(size_t)g * TOT + q]);
    float d = sqrtf(2.0f * fmaxf(m, 0.0f));
#pragma unroll
    for (int off = 32; off > 0; off >>= 1) d += __shfl_down(d, off);
    __shared__ float r[4];
    if ((threadIdx.x & 63) == 0) r[threadIdx.x >> 6] = d;
    __syncthreads();
    if (threadIdx.x == 0)
        atomicAdd(out, (r[0] + r[1] + r[2] + r[3]) * (1.0f / (float)NQ));
}

extern "C" void kernel_launch(void* const* d_in, const int* in_sizes, int n_in,
                              void* d_out, int out_size, void* d_ws, size_t ws_size,
                              hipStream_t stream) {
    const float* pred = (const float*)d_in[0];  // [B,N,3]
    const float* tgt  = (const float*)d_in[1];  // [B,M,3]
    float* out = (float*)d_out;

    float* part = (float*)d_ws;                 // NJT*TOT floats = 4 MB

    dim3 grid1(ITILES * NJT, B_SZ, 2);
    chamfer_partial_kernel<<<grid1, THREADS, 0, stream>>>(pred, tgt, part, out);
    chamfer_combine_kernel<<<NBLK2, 256, 0, stream>>>(part, out);
}

// Round 2
// 81.711 us; speedup vs baseline: 1.0252x; 1.0252x over previous
//
#include <hip/hip_runtime.h>
#include <math.h>

// Problem shape (fixed by harness setup_inputs): B=8, N=M=4096, D=3, fp32.
#define B_SZ 8
#define N_SZ 4096
#define M_SZ 4096
#define NQ (B_SZ * N_SZ)            // 32768 queries per direction
#define TOT (2 * NQ)                // 65536 total queries

#define THREADS 256
#define QPT 4                       // queries per thread (2 packed f32x2 slots)
#define SLOTS (QPT / 2)
#define QPB (THREADS * QPT)         // 1024 queries per block
#define ITILES (N_SZ / QPB)         // 4
#define JTILE 256                   // targets staged in LDS per block
#define NJT (M_SZ / JTILE)          // 16 target tiles (= partials per query)

#define NBLK2 (TOT / 256)           // 256 phase-2 blocks

typedef float f32x2 __attribute__((ext_vector_type(2)));

// ws layout (floats): part[g * TOT + q], g in [0,NJT) -> 4 MB.
// Every slot is written by phase 1, so no ws init is needed (harness poison
// irrelevant). No ws atomics.
//
// score(q,t) = t^2/2 - q.t ; after the tile loop we add q^2/2 -> d^2/2.
//
// Round-0 proven inner loop (query-packed slots, 2.5 VALU issue/pair).
// Change vs round 0: QPT 8->4 doubles the grid (512 -> 1024 blocks,
// 2 -> 4 waves/SIMD) for latency hiding at identical per-pair issue cost;
// phase 2+3 fused via one uncontended atomicAdd per block.
//
// grid: x = ITILES*NJT (64), y = B (8), z = dir (2)  -> 1024 blocks.
__global__ __launch_bounds__(THREADS)
void chamfer_partial_kernel(const float* __restrict__ pred,
                            const float* __restrict__ tgt,
                            float* __restrict__ part,
                            float* __restrict__ out)
{
    const int b   = blockIdx.y;
    const int dir = blockIdx.z;

    // Zero the output accumulator for phase 2's atomics (stream-ordered:
    // this kernel fully completes before phase 2 starts).
    if (blockIdx.x == 0 && b == 0 && dir == 0 && threadIdx.x == 0)
        out[0] = 0.0f;

    const float* Q;
    const float* Db;
    int qoff;
    if (dir == 0) { Q = pred + (size_t)b * N_SZ * 3; Db = tgt  + (size_t)b * M_SZ * 3; qoff = b * N_SZ; }
    else          { Q = tgt  + (size_t)b * M_SZ * 3; Db = pred + (size_t)b * N_SZ * 3; qoff = NQ + b * M_SZ; }

    const int itile = blockIdx.x >> 4;          // / NJT
    const int g     = blockIdx.x & (NJT - 1);

    __shared__ float4 sp[JTILE];                // x,y,z,h  (h = |t|^2 / 2)
    {
        const float* s = Db + (size_t)(g * JTILE + threadIdx.x) * 3;
        float x = s[0], y = s[1], z = s[2];
        sp[threadIdx.x] = make_float4(x, y, z, 0.5f * (x * x + y * y + z * z));
    }
    __syncthreads();

    // 4 queries per thread: negated coords packed 2-per-f32x2; q^2/2 kept
    // to fold in after the tile loop (so phase 2 never reads the points).
    f32x2 qxn[SLOTS], qyn[SLOTS], qzn[SLOTS], q2h[SLOTS], mn[SLOTS];
    const int qbase = itile * QPB + threadIdx.x;
#pragma unroll
    for (int s = 0; s < SLOTS; ++s) {
        const int i0 = qbase + (2 * s) * THREADS;
        const int i1 = qbase + (2 * s + 1) * THREADS;
        float x0 = Q[i0 * 3 + 0], y0 = Q[i0 * 3 + 1], z0 = Q[i0 * 3 + 2];
        float x1 = Q[i1 * 3 + 0], y1 = Q[i1 * 3 + 1], z1 = Q[i1 * 3 + 2];
        qxn[s] = { -x0, -x1 };
        qyn[s] = { -y0, -y1 };
        qzn[s] = { -z0, -z1 };
        q2h[s] = { 0.5f * (x0 * x0 + y0 * y0 + z0 * z0),
                   0.5f * (x1 * x1 + y1 * y1 + z1 * z1) };
        mn[s]  = { 3.0e38f, 3.0e38f };
    }

    // Inner loop: 1 broadcast ds_read_b128; per slot 3 pk_fma + 2 v_min_f32
    // -> 2.5 VALU issue slots per point-pair.
#pragma unroll 8
    for (int j = 0; j < JTILE; ++j) {
        float4 t = sp[j];
        f32x2 tx = { t.x, t.x };
        f32x2 ty = { t.y, t.y };
        f32x2 tz = { t.z, t.z };
        f32x2 th = { t.w, t.w };
#pragma unroll
        for (int s = 0; s < SLOTS; ++s) {
            f32x2 sc = th + qxn[s] * tx;
            sc += qyn[s] * ty;
            sc += qzn[s] * tz;
            mn[s].x = fminf(mn[s].x, sc.x);
            mn[s].y = fminf(mn[s].y, sc.y);
        }
    }

    // Fold q^2/2 -> partial d^2/2; plain coalesced stores (no atomics).
    float* pg = part + (size_t)g * TOT + qoff;
#pragma unroll
    for (int s = 0; s < SLOTS; ++s) {
        f32x2 v = mn[s] + q2h[s];
        pg[qbase + (2 * s) * THREADS]     = v.x;
        pg[qbase + (2 * s + 1) * THREADS] = v.y;
    }
}

// Phase 2 (phase 3 fused in): one query per thread; 16 coalesced loads;
// block sum; one atomicAdd per block (256 total, no contention).
__global__ __launch_bounds__(256)
void chamfer_combine_kernel(const float* __restrict__ part,
                            float* __restrict__ out)
{
    const int q = blockIdx.x * 256 + threadIdx.x;
    float m = 3.0e38f;
#pragma unroll
    for (int g = 0; g < NJT; ++g) m = fminf(m, part[(size_t)g * TOT + q]);
    float d = sqrtf(2.0f * fmaxf(m, 0.0f));
#pragma unroll
    for (int off = 32; off > 0; off >>= 1) d += __shfl_down(d, off);
    __shared__ float r[4];
    if ((threadIdx.x & 63) == 0) r[threadIdx.x >> 6] = d;
    __syncthreads();
    if (threadIdx.x == 0)
        atomicAdd(out, (r[0] + r[1] + r[2] + r[3]) * (1.0f / (float)NQ));
}

extern "C" void kernel_launch(void* const* d_in, const int* in_sizes, int n_in,
                              void* d_out, int out_size, void* d_ws, size_t ws_size,
                              hipStream_t stream) {
    const float* pred = (const float*)d_in[0];  // [B,N,3]
    const float* tgt  = (const float*)d_in[1];  // [B,M,3]
    float* out = (float*)d_out;

    float* part = (float*)d_ws;                 // NJT*TOT floats = 4 MB

    dim3 grid1(ITILES * NJT, B_SZ, 2);
    chamfer_partial_kernel<<<grid1, THREADS, 0, stream>>>(pred, tgt, part, out);
    chamfer_combine_kernel<<<NBLK2, 256, 0, stream>>>(part, out);
}

// Round 3
// 81.708 us; speedup vs baseline: 1.0252x; 1.0000x over previous
//
#include <hip/hip_runtime.h>
#include <math.h>

// Problem shape (fixed by harness setup_inputs): B=8, N=M=4096, D=3, fp32.
#define B_SZ 8
#define N_SZ 4096
#define M_SZ 4096
#define NQ (B_SZ * N_SZ)            // 32768 queries per direction
#define TOT (2 * NQ)                // 65536 total queries

#define THREADS 256
#define QPT 8                       // queries per thread (4 packed f32x2 slots)
#define SLOTS (QPT / 2)
#define QPB (THREADS * QPT)         // 2048 queries per block
#define ITILES (N_SZ / QPB)         // 2
#define JTILE 128                   // targets staged in LDS per block
#define NJT (M_SZ / JTILE)          // 32 target tiles (= partials per query)

#define NBLK2 (TOT / 256)           // 256 phase-2 blocks

typedef float f32x2 __attribute__((ext_vector_type(2)));

// ws layout (floats): part[g * TOT + q], g in [0,NJT) -> 8 MB.
// Every slot is written by phase 1, so no ws init is needed (harness poison
// irrelevant). No ws atomics.
//
// score(q,t) = t^2/2 - q.t ; after the tile loop we add q^2/2 -> d^2/2.
//
// R0-proven inner loop (QPT=8, 4 slots of ILP, 2.5 VALU issue/pair).
// Change vs R0: JTILE 256->128 doubles the grid (512 -> 1024 blocks,
// 2 -> 4 waves/SIMD) WITHOUT touching per-thread ILP — R2 showed that
// trading ILP for TLP (QPT 8->4) is a net loss; this keeps both.
//
// grid: x = ITILES*NJT (64), y = B (8), z = dir (2)  -> 1024 blocks.
__global__ __launch_bounds__(THREADS)
void chamfer_partial_kernel(const float* __restrict__ pred,
                            const float* __restrict__ tgt,
                            float* __restrict__ part,
                            float* __restrict__ out)
{
    const int b   = blockIdx.y;
    const int dir = blockIdx.z;

    // Zero the output accumulator for phase 2's atomics (stream-ordered:
    // this kernel fully completes before phase 2 starts).
    if (blockIdx.x == 0 && b == 0 && dir == 0 && threadIdx.x == 0)
        out[0] = 0.0f;

    const float* Q;
    const float* Db;
    int qoff;
    if (dir == 0) { Q = pred + (size_t)b * N_SZ * 3; Db = tgt  + (size_t)b * M_SZ * 3; qoff = b * N_SZ; }
    else          { Q = tgt  + (size_t)b * M_SZ * 3; Db = pred + (size_t)b * N_SZ * 3; qoff = NQ + b * M_SZ; }

    const int itile = blockIdx.x >> 5;          // / NJT
    const int g     = blockIdx.x & (NJT - 1);

    __shared__ float4 sp[JTILE];                // x,y,z,h  (h = |t|^2 / 2)
    if (threadIdx.x < JTILE) {
        const float* s = Db + (size_t)(g * JTILE + threadIdx.x) * 3;
        float x = s[0], y = s[1], z = s[2];
        sp[threadIdx.x] = make_float4(x, y, z, 0.5f * (x * x + y * y + z * z));
    }
    __syncthreads();

    // 8 queries per thread: negated coords packed 2-per-f32x2; q^2/2 kept
    // to fold in after the tile loop (so phase 2 never reads the points).
    f32x2 qxn[SLOTS], qyn[SLOTS], qzn[SLOTS], q2h[SLOTS], mn[SLOTS];
    const int qbase = itile * QPB + threadIdx.x;
#pragma unroll
    for (int s = 0; s < SLOTS; ++s) {
        const int i0 = qbase + (2 * s) * THREADS;
        const int i1 = qbase + (2 * s + 1) * THREADS;
        float x0 = Q[i0 * 3 + 0], y0 = Q[i0 * 3 + 1], z0 = Q[i0 * 3 + 2];
        float x1 = Q[i1 * 3 + 0], y1 = Q[i1 * 3 + 1], z1 = Q[i1 * 3 + 2];
        qxn[s] = { -x0, -x1 };
        qyn[s] = { -y0, -y1 };
        qzn[s] = { -z0, -z1 };
        q2h[s] = { 0.5f * (x0 * x0 + y0 * y0 + z0 * z0),
                   0.5f * (x1 * x1 + y1 * y1 + z1 * z1) };
        mn[s]  = { 3.0e38f, 3.0e38f };
    }

    // Inner loop: 1 broadcast ds_read_b128; per slot 3 pk_fma + 2 v_min_f32
    // -> 2.5 VALU issue slots per point-pair, 4 independent slot chains.
#pragma unroll 8
    for (int j = 0; j < JTILE; ++j) {
        float4 t = sp[j];
        f32x2 tx = { t.x, t.x };
        f32x2 ty = { t.y, t.y };
        f32x2 tz = { t.z, t.z };
        f32x2 th = { t.w, t.w };
#pragma unroll
        for (int s = 0; s < SLOTS; ++s) {
            f32x2 sc = th + qxn[s] * tx;
            sc += qyn[s] * ty;
            sc += qzn[s] * tz;
            mn[s].x = fminf(mn[s].x, sc.x);
            mn[s].y = fminf(mn[s].y, sc.y);
        }
    }

    // Fold q^2/2 -> partial d^2/2; plain coalesced stores (no atomics).
    float* pg = part + (size_t)g * TOT + qoff;
#pragma unroll
    for (int s = 0; s < SLOTS; ++s) {
        f32x2 v = mn[s] + q2h[s];
        pg[qbase + (2 * s) * THREADS]     = v.x;
        pg[qbase + (2 * s + 1) * THREADS] = v.y;
    }
}

// Phase 2 (phase 3 fused in): one query per thread; 32 coalesced loads;
// block sum; one atomicAdd per block (256 total, no contention).
__global__ __launch_bounds__(256)
void chamfer_combine_kernel(const float* __restrict__ part,
                            float* __restrict__ out)
{
    const int q = blockIdx.x * 256 + threadIdx.x;
    float m = 3.0e38f;
#pragma unroll
    for (int g = 0; g < NJT; ++g) m = fminf(m, part[(size_t)g * TOT + q]);
    float d = sqrtf(2.0f * fmaxf(m, 0.0f));
#pragma unroll
    for (int off = 32; off > 0; off >>= 1) d += __shfl_down(d, off);
    __shared__ float r[4];
    if ((threadIdx.x & 63) == 0) r[threadIdx.x >> 6] = d;
    __syncthreads();
    if (threadIdx.x == 0)
        atomicAdd(out, (r[0] + r[1] + r[2] + r[3]) * (1.0f / (float)NQ));
}

extern "C" void kernel_launch(void* const* d_in, const int* in_sizes, int n_in,
                              void* d_out, int out_size, void* d_ws, size_t ws_size,
                              hipStream_t stream) {
    const float* pred = (const float*)d_in[0];  // [B,N,3]
    const float* tgt  = (const float*)d_in[1];  // [B,M,3]
    float* out = (float*)d_out;

    float* part = (float*)d_ws;                 // NJT*TOT floats = 8 MB

    dim3 grid1(ITILES * NJT, B_SZ, 2);
    chamfer_partial_kernel<<<grid1, THREADS, 0, stream>>>(pred, tgt, part, out);
    chamfer_combine_kernel<<<NBLK2, 256, 0, stream>>>(part, out);
}